// Round 2
// baseline (23.540 us; speedup 1.0000x reference)
//
#include <hip/hip_runtime.h>

// Problem constants (match reference)
#define NTOT 512   // N
#define NH   448   // N - K (head rows, identity part)
#define KK   64    // K (solved rows)
#define NL   30688 // strictly-lower entries in last K rows
#define DD   16    // domains
#define SLICES 32  // blocks per domain (power of 2)
#define MAXG   8   // samples processed per group iteration
#define LISTCAP 32 // max samples per slice: 1024/SLICES

// z = F_d eps, F_d = (I-L)^{-1} S  <=>  (I-L) z = S eps (forward substitution).
// Head rows (<448): z_j = eps_j. Tail rows 448+r:
//   y_r = s_r*eps_{448+r} + dot(Trow_r, eps[0:448]);  z = (I-U)^{-1} y
// Trow_r = L_emb[dom] + 448r + r(r-1)/2 (448 floats); U[r][m] at +448+m.
// Blocks are (domain, slice): each block scans d[] once (4 KB, L2-hit),
// claims every SLICES-th matching sample, and amortizes T/U reads over them.
__global__ __launch_bounds__(512)
void fvae_kernel(const float* __restrict__ eps,      // [B,512]
                 const int*   __restrict__ dom_idx,  // [B]
                 const float* __restrict__ L_emb,    // [16, NL]
                 const float* __restrict__ S_emb,    // [16, 64]
                 const float* __restrict__ bias_ns,  // [16, 64]
                 const float* __restrict__ bias_sh,  // [448]
                 float*       __restrict__ out,      // [B,512]
                 int B)
{
    const int dom   = blockIdx.x & (DD - 1);
    const int slice = blockIdx.x / DD;
    const int tid   = threadIdx.x;
    const int lane  = tid & 63;
    const int wave  = tid >> 6;

    __shared__ int   list_s[LISTCAP];
    __shared__ int   cnt_s;
    __shared__ float eps_s[MAXG][NTOT];
    __shared__ float y_s[MAXG][KK];
    __shared__ float U_s[KK][KK + 1];   // padded: conflict-free per-lane-row reads

    // ---- scan d[] (wave 0): ordered enumeration of samples with dom_idx==dom
    if (wave == 0) {
        int base = 0;
        for (int t = 0; t < B / 64; ++t) {
            const int pos = t * 64 + lane;
            const int dm  = dom_idx[pos];
            const unsigned long long m = __ballot(dm == dom);
            if (dm == dom) {
                const int rank = base + __popcll(m & ((1ull << lane) - 1ull));
                if ((rank & (SLICES - 1)) == slice) {
                    const int q = rank / SLICES;
                    if (q < LISTCAP) list_s[q] = pos;
                }
            }
            base += __popcll(m);
        }
        if (lane == 0)
            cnt_s = (base > slice) ? (base - 1 - slice) / SLICES + 1 : 0;
    }

    // ---- stage U (64x64 strictly-lower block) once per block
    const float* __restrict__ Ld = L_emb + (size_t)dom * NL;
    if (dom != 0) {
        for (int r = wave; r < KK; r += 8)
            if (lane < r)
                U_s[r][lane] = Ld[r * NH + (r * (r - 1)) / 2 + NH + lane];
    }
    __syncthreads();

    const int G_total = cnt_s;
    if (G_total == 0) return;

    for (int s0 = 0; s0 < G_total; s0 += MAXG) {
        const int Gc = min(MAXG, G_total - s0);

        // stage eps rows for this group (coalesced)
        for (int idx = tid; idx < Gc * NTOT; idx += 512) {
            const int g = idx / NTOT, j = idx & (NTOT - 1);
            eps_s[g][j] = eps[(size_t)list_s[s0 + g] * NTOT + j];
        }
        __syncthreads();

        // head output: z_j = eps_j + bias_shared_j
        for (int g = 0; g < Gc; ++g)
            if (tid < NH)
                out[(size_t)list_s[s0 + g] * NTOT + tid] = eps_s[g][tid] + bias_sh[tid];

        // phase 2: y[g][r] = s_r*eps_g[448+r] + dot(Trow_r, eps_g[0:448])
        if (dom != 0) {
            for (int r = wave; r < KK; r += 8) {
                const float* __restrict__ Lr = Ld + r * NH + (r * (r - 1)) / 2;
                float l0 = Lr[lane];
                float l1 = Lr[lane + 64];
                float l2 = Lr[lane + 128];
                float l3 = Lr[lane + 192];
                float l4 = Lr[lane + 256];
                float l5 = Lr[lane + 320];
                float l6 = Lr[lane + 384];
                const float sr = S_emb[dom * KK + r];
                for (int g = 0; g < Gc; ++g) {
                    float acc = l0 * eps_s[g][lane]
                              + l1 * eps_s[g][lane + 64]
                              + l2 * eps_s[g][lane + 128]
                              + l3 * eps_s[g][lane + 192]
                              + l4 * eps_s[g][lane + 256]
                              + l5 * eps_s[g][lane + 320]
                              + l6 * eps_s[g][lane + 384];
                    #pragma unroll
                    for (int s = 32; s; s >>= 1)
                        acc += __shfl_xor(acc, s);
                    if (lane == 0)
                        y_s[g][r] = sr * eps_s[g][NH + r] + acc;
                }
            }
        }
        __syncthreads();

        // phase 3: z = (I-U)^{-1} y, one sample per wave (lane = row)
        if (dom != 0) {
            for (int g = wave; g < Gc; g += 8) {
                const int m = lane;
                float z = y_s[g][m];
                #pragma unroll
                for (int r = 0; r < KK - 1; ++r) {
                    const float u  = (r < m) ? U_s[m][r] : 0.f;
                    const float zr = __shfl(z, r);  // lane r's z final by step r
                    z += u * zr;
                }
                out[(size_t)list_s[s0 + g] * NTOT + NH + m] = z + bias_ns[dom * KK + m];
            }
        } else {
            // domain 0: L=0, S=I -> z_tail = eps_tail
            for (int g = wave; g < Gc; g += 8)
                out[(size_t)list_s[s0 + g] * NTOT + NH + lane] =
                    eps_s[g][NH + lane] + bias_ns[lane];
        }
        __syncthreads();  // protect eps_s / y_s before next group
    }
}

extern "C" void kernel_launch(void* const* d_in, const int* in_sizes, int n_in,
                              void* d_out, int out_size, void* d_ws, size_t ws_size,
                              hipStream_t stream) {
    const float* eps     = (const float*)d_in[0];
    const int*   dom     = (const int*)  d_in[1];
    const float* L_emb   = (const float*)d_in[2];
    const float* S_emb   = (const float*)d_in[3];
    const float* bias_ns = (const float*)d_in[4];
    const float* bias_sh = (const float*)d_in[5];
    float* out = (float*)d_out;

    const int B = in_sizes[0] / NTOT;  // 1024
    fvae_kernel<<<dim3(DD * SLICES), dim3(512), 0, stream>>>(
        eps, dom, L_emb, S_emb, bias_ns, bias_sh, out, B);
}